// Round 13
// baseline (175.773 us; speedup 1.0000x reference)
//
#include <hip/hip_runtime.h>
#include <hip/hip_bf16.h>

#define LAMBDA_INIT_F 0.35550906759096927f
#define ONE_MINUS_LI  0.64449093240903073f
#define QSCALE 0.36067376022224085f   // 0.25 * log2(e): exp(s) == exp2(s_scaled)

typedef unsigned short u16;
typedef unsigned int   u32;
typedef short s4v  __attribute__((ext_vector_type(4)));
typedef float f16v __attribute__((ext_vector_type(16)));

__device__ __forceinline__ u16 f2bf(float f) {
    __hip_bfloat16 h = __float2bfloat16(f);
    return *reinterpret_cast<u16*>(&h);
}
__device__ __forceinline__ u32 pk2bf(float lo, float hi) {
    return (u32)f2bf(lo) | ((u32)f2bf(hi) << 16);
}
union U2S { u32 u[2]; s4v s; };
__device__ __forceinline__ s4v mks4(u32 a, u32 b) { U2S x; x.u[0]=a; x.u[1]=b; return x.s; }

// raw v_exp_f32 (1 inst) — libm exp2f is ~8 inst without -ffast-math
__device__ __forceinline__ float fexp2(float x) {
#if __has_builtin(__builtin_amdgcn_exp2f)
    return __builtin_amdgcn_exp2f(x);
#else
    float r; asm volatile("v_exp_f32 %0, %1\n\ts_nop 1" : "=v"(r) : "v"(x)); return r;
#endif
}

#define MFMA(a,b,c) __builtin_amdgcn_mfma_f32_32x32x8bf16_1k((a),(b),(c),0,0,0)

// ---------------------------------------------------------------------------
// Kernel 0: prep. Blocks 0..79: transpose f32 weights -> bf16 WT[1280][256]
// (16 WT-rows per block). Blocks 80..143: x (f32) -> xbf (bf16), 64 rows each.
// ---------------------------------------------------------------------------
__global__ __launch_bounds__(256) void prep_kernel(
    const float* __restrict__ Wq, const float* __restrict__ Wkv,
    const float* __restrict__ Wg, const float* __restrict__ Wout,
    const float* __restrict__ x,
    u16* __restrict__ WT, u16* __restrict__ xbf)
{
    const int bid = blockIdx.x;
    const int tid = threadIdx.x;

    if (bid >= 80) {               // x convert: rows (bid-80)*64 .. +63
        const int r0 = (bid - 80) * 64;
        const float2* src = (const float2*)(x + (size_t)r0 * 256);
        u32* dst = (u32*)(xbf + (size_t)r0 * 256);
        for (int idx = tid; idx < 64 * 128; idx += 256) {
            float2 v = src[idx];
            dst[idx] = pk2bf(v.x, v.y);
        }
        return;
    }

    __shared__ u16 tile[16 * 258];
    const int n0g = bid * 16;      // WT row base (0..1279)
    const float* src; int cols; int ncol0;
    if      (n0g < 256)  { src = Wq;   cols = 256; ncol0 = n0g; }
    else if (n0g < 768)  { src = Wkv;  cols = 512; ncol0 = n0g - 256; }
    else if (n0g < 1024) { src = Wg;   cols = 256; ncol0 = n0g - 768; }
    else                 { src = Wout; cols = 256; ncol0 = n0g - 1024; }

    const float* srow = src + (size_t)tid * cols + ncol0;
#pragma unroll
    for (int j = 0; j < 8; ++j) {
        const float2 v = *(const float2*)(srow + 2*j);
        tile[(2*j + 0) * 258 + tid] = f2bf(v.x);
        tile[(2*j + 1) * 258 + tid] = f2bf(v.y);
    }
    __syncthreads();

    const u32* t32 = (const u32*)tile;           // row stride 129 u32
    const int nn = tid >> 4, part = tid & 15;
    u32* dst = (u32*)WT + (size_t)(n0g + nn) * 128 + part * 8;
    const u32* s2 = t32 + nn * 129 + part * 8;
#pragma unroll
    for (int j = 0; j < 8; ++j) dst[j] = s2[j];
}

// ---------------------------------------------------------------------------
// Kernel 1: MFMA projections. C[4096,1024] = xbf @ [Wq|Wk|Wv|Wg], epilogue
// scatters to Qb (bf16, pre-scaled QSCALE), Kb, Vb (bf16), Gb (f32 sigmoid).
// Grid 512 = 32 mt x 16 nt; 4 waves, wave w = rows mt*128+w*32, 2 n-subtiles.
// ---------------------------------------------------------------------------
__global__ __launch_bounds__(256) void proj_kernel(
    const u16* __restrict__ x, const u16* __restrict__ WT,
    const float* __restrict__ bg,
    u16* __restrict__ Qb, u16* __restrict__ Kb,
    u16* __restrict__ Vb, float* __restrict__ Gb)
{
    const int bid = blockIdx.x;
    const int nt = bid & 15, mt = bid >> 4;
    const int tid = threadIdx.x, w = tid >> 6, lane = tid & 63;
    const int l31 = lane & 31, hh = lane >> 5;
    const int m0 = mt * 128 + w * 32;
    const int n0 = nt * 64;

    const u16* xr  = x  + (size_t)(m0 + l31) * 256 + 4*hh;
    const u16* br0 = WT + (size_t)(n0 + l31) * 256 + 4*hh;
    const u16* br1 = WT + (size_t)(n0 + 32 + l31) * 256 + 4*hh;

    f16v a0, a1;
#pragma unroll
    for (int r = 0; r < 16; ++r) { a0[r] = 0.f; a1[r] = 0.f; }

#pragma unroll
    for (int ks = 0; ks < 16; ++ks) {
        s4v xa  = *(const s4v*)(xr  + ks*16);
        s4v xb  = *(const s4v*)(xr  + ks*16 + 8);
        s4v w0a = *(const s4v*)(br0 + ks*16);
        s4v w0b = *(const s4v*)(br0 + ks*16 + 8);
        s4v w1a = *(const s4v*)(br1 + ks*16);
        s4v w1b = *(const s4v*)(br1 + ks*16 + 8);
        a0 = MFMA(xa, w0a, a0); a0 = MFMA(xb, w0b, a0);
        a1 = MFMA(xa, w1a, a1); a1 = MFMA(xb, w1b, a1);
    }

    const int cat = nt >> 2;    // 0=Q 1=K 2=V 3=G
#pragma unroll
    for (int ns = 0; ns < 2; ++ns) {
        const f16v& acc = ns ? a1 : a0;
        const int n = nt * 64 + ns * 32 + l31;
#pragma unroll
        for (int r = 0; r < 16; ++r) {
            const int il = (r & 3) + 8*(r >> 2) + 4*hh;
            const int R = m0 + il;
            const int b = R >> 11, i = R & 2047;
            const float v = acc[r];
            if (cat == 0) {
                const int h = n >> 4, d = n & 15;
                Qb[((size_t)(b*16 + h) * 2048 + i) * 16 + d] = f2bf(v * QSCALE);
            } else if (cat == 1) {
                const int nk = n - 256, h = nk >> 4, d = nk & 15;
                Kb[((size_t)(b*16 + h) * 2048 + i) * 16 + d] = f2bf(v);
            } else if (cat == 2) {
                const int nv = n - 512, hv = nv >> 5, d2 = nv & 31;
                Vb[((size_t)(b*8 + hv) * 2048 + i) * 32 + d2] = f2bf(v);
            } else {
                const int gcol = n - 768;
                const float t = v + bg[gcol];
                Gb[(size_t)R * 256 + gcol] = 1.0f / (1.0f + __expf(-t));
            }
        }
    }
}

// ---------------------------------------------------------------------------
// Kernel 2: MFMA flash differential attention + LN + gate -> bf16 A.
// Grid 512 = (b, ho, 64-q-rows). 4 waves = (it = w>>1, s = w&1): wave handles
// i-tile it (32 rows), subhead s, and sweeps ALL 64 j-chunks. Each staged
// chunk (K1 32x16 + K2 32x16 + V^T 32x32) is shared by all 4 waves -> total
// staging & K/V fetch HALVED vs the 32-row-block version. Double-buffered;
// per-chunk stage spread over all 256 threads. S^T = MFMA(A=K, B=Q);
// P = exp2 via raw v_exp_f32, truncation-packed (v_perm) into the PV
// A-operand. 2-way (s) cross-wave combine + diff + LN + gate via LDS.
// ---------------------------------------------------------------------------
__global__ __launch_bounds__(256) void attn_kernel(
    const u16* __restrict__ Q, const u16* __restrict__ K,
    const u16* __restrict__ V, const float* __restrict__ G,
    const float* __restrict__ lq1, const float* __restrict__ lk1,
    const float* __restrict__ lq2, const float* __restrict__ lk2,
    const float* __restrict__ gamma, const float* __restrict__ beta,
    u16* __restrict__ A)
{
    // staging: 2 buf x (K0 288 + K1 288 + V^T 544) u32 = 2240 u32 = 8.96 KB
    // combine (reuse after loop): 4 x (32x33 f32) O + 4x32 f32 l = 4352 f32
    __shared__ float smemf[4480];
    u16* st  = (u16*)smemf;
    u32* stu = (u32*)smemf;

    const int bid = blockIdx.x;
    const int itile = bid & 31;
    const int combo = bid >> 5;
    const int ho = combo & 7, b = combo >> 3;
    const int i0 = itile * 64;

    const int tid = threadIdx.x, w = tid >> 6, lane = tid & 63;
    const int l31 = lane & 31, hh = lane >> 5;
    const int s = w & 1, it = w >> 1;
    const int i0w = i0 + it * 32;

    const u16* Vg = V + (size_t)(b*8 + ho) * 2048 * 32;
    const u16* Qg = Q + ((size_t)(b*16 + 2*ho + s) * 2048 + (i0w + l31)) * 16;
    const s4v qf0 = *(const s4v*)(Qg + 4*hh);
    const s4v qf1 = *(const s4v*)(Qg + 8 + 4*hh);

    // --- staging assignment (per thread, per chunk of 32 keys) ---
    // K: 2 subheads x 32 rows x 8 u32; thread -> (ksub, krow, kseg): 2 u32
    const int ksub = tid >> 7, krow = (tid >> 2) & 31, kseg = tid & 3;
    const u32* kgp = (const u32*)(K + (size_t)(b*16 + 2*ho + ksub) * 2048 * 16)
                     + (size_t)krow * 8 + kseg * 2;
    // V: 32 rows(j) x 16 u32; thread -> (vj, vd4): 2 u32 = d vd4..vd4+3
    const int vj = tid >> 3, vd4 = (tid & 7) * 4;
    const u32* vgp = (const u32*)Vg + (size_t)vj * 16 + (tid & 7) * 2;

    // LDS offsets (u32 view; buffer stride 1120 u32):
    const int kw_off = ksub*288 + krow*9 + kseg*2;        // + p*1120
    const int kr_off = s*288 + l31*9 + 2*hh;              // + p*1120
    const int vr_off = 576 + l31*17;                      // + p*1120; + 4f+2hh
    // V write (u16 view; buffer stride 2240 u16): 1152 + d*34 + vj
    const int vw_u16 = 1152 + vd4*34 + vj;                // + p*2240; rows +34

    f16v oacc;
#pragma unroll
    for (int r = 0; r < 16; ++r) oacc[r] = 0.f;
    float la0 = 0.f, la1 = 0.f;

    {   // prologue: stage chunk 0 into buffer 0
        u32 k0 = kgp[0], k1 = kgp[1];
        u32 v0 = vgp[0], v1 = vgp[1];
        u32* kd = stu + kw_off;
        kd[0] = k0; kd[1] = k1;
        u16* vd = st + vw_u16;
        vd[0]    = (u16)(v0 & 0xffff); vd[34]    = (u16)(v0 >> 16);
        vd[68]   = (u16)(v1 & 0xffff); vd[102]   = (u16)(v1 >> 16);
    }

    for (int c = 0; c < 64; ++c) {
        __syncthreads();
        const int p = c & 1, pn = 1 - p;
        const int cc = (c + 1) & 63;            // branchless: last iter re-reads 0

        const u32* kp = kgp + (size_t)cc * 256;
        u32 nk0 = kp[0], nk1 = kp[1];
        const u32* vp = vgp + (size_t)cc * 512;
        u32 nv0 = vp[0], nv1 = vp[1];

        const u32* kb2 = stu + p*1120 + kr_off;
        const u32* vb2 = stu + p*1120 + vr_off;

        f16v sc;
#pragma unroll
        for (int r = 0; r < 16; ++r) sc[r] = 0.f;
        {
            s4v kf0 = mks4(kb2[0], kb2[1]);
            sc = MFMA(kf0, qf0, sc);
            s4v kf1 = mks4(kb2[4], kb2[5]);
            sc = MFMA(kf1, qf1, sc);
        }
        float pv[16];
#pragma unroll
        for (int r = 0; r < 16; ++r) pv[r] = fexp2(sc[r]);
        la0 += pv[0];  la0 += pv[1];  la0 += pv[2];  la0 += pv[3];
        la1 += pv[4];  la1 += pv[5];  la1 += pv[6];  la1 += pv[7];
        la0 += pv[8];  la0 += pv[9];  la0 += pv[10]; la0 += pv[11];
        la1 += pv[12]; la1 += pv[13]; la1 += pv[14]; la1 += pv[15];
#pragma unroll
        for (int f = 0; f < 4; ++f) {
            u32 plo = __builtin_amdgcn_perm(__float_as_uint(pv[4*f+1]),
                                            __float_as_uint(pv[4*f+0]), 0x07060302);
            u32 phi = __builtin_amdgcn_perm(__float_as_uint(pv[4*f+3]),
                                            __float_as_uint(pv[4*f+2]), 0x07060302);
            s4v pf = mks4(plo, phi);
            s4v vf = mks4(vb2[4*f + 2*hh], vb2[4*f + 2*hh + 1]);
            oacc = MFMA(pf, vf, oacc);
        }

        {   // stage chunk cc into buffer pn
            u32* kd = stu + pn*1120 + kw_off;
            kd[0] = nk0; kd[1] = nk1;
            u16* vd = st + pn*2240 + vw_u16;
            vd[0]  = (u16)(nv0 & 0xffff); vd[34]  = (u16)(nv0 >> 16);
            vd[68] = (u16)(nv1 & 0xffff); vd[102] = (u16)(nv1 >> 16);
        }
    }
    const float lacc = la0 + la1;

    __syncthreads();                  // staging dead; reuse LDS for combine
    float ltot = lacc + __shfl_xor(lacc, 32);
    float* ob = smemf + w * 1056;
#pragma unroll
    for (int r = 0; r < 16; ++r) {
        const int il = (r & 3) + 8*(r >> 2) + 4*hh;   // local query row
        ob[il*33 + l31] = oacc[r];                    // col = d = l31
    }
    if (lane < 32) smemf[4224 + w*32 + l31] = ltot;
    __syncthreads();

    if (tid < 64) {
        const int it2 = tid >> 5, ii = tid & 31;
        const float l1 = smemf[4224 + (2*it2 + 0)*32 + ii];   // s=0 wave
        const float l2 = smemf[4224 + (2*it2 + 1)*32 + ii];   // s=1 wave
        const float* o1 = smemf + (2*it2 + 0)*1056 + ii*33;
        const float* o2 = smemf + (2*it2 + 1)*1056 + ii*33;

        float sA = 0.f, sB = 0.f;
#pragma unroll
        for (int d = 0; d < 16; ++d) {
            sA += lq1[d] * lk1[d];
            sB += lq2[d] * lk2[d];
        }
        const float lam = __expf(sA) - __expf(sB) + LAMBDA_INIT_F;
        const float c1 = 1.f / l1, c2 = lam / l2;

        float od[32], mu = 0.f;
#pragma unroll
        for (int d = 0; d < 32; ++d) {
            od[d] = o1[d] * c1 - o2[d] * c2;
            mu += od[d];
        }
        mu *= (1.f / 32.f);
        float var = 0.f;
#pragma unroll
        for (int d = 0; d < 32; ++d) { const float t2 = od[d] - mu; var += t2 * t2; }
        var *= (1.f / 32.f);
        const float rs = rsqrtf(var + 1e-5f);

        const int R = b*2048 + i0 + it2*32 + ii;
        const float* Gr = G + (size_t)R * 256 + ho*32;
        u16* Ar = A + (size_t)R * 256 + ho*32;
#pragma unroll
        for (int d = 0; d < 32; ++d) {
            const float val = (od[d] - mu)*rs*gamma[d] + beta[d];
            Ar[d] = f2bf(val * ONE_MINUS_LI * Gr[d]);
        }
    }
}

// ---------------------------------------------------------------------------
// Kernel 3: out = A(bf16) @ Wout + bout -> f32. Grid 256, 512 threads:
// 8 waves = 4 (32x32) tiles x 2 K-halves; LDS combine of the K-split.
// ---------------------------------------------------------------------------
__global__ __launch_bounds__(512) void out_kernel(
    const u16* __restrict__ Abf, const u16* __restrict__ WT,
    const float* __restrict__ bout, float* __restrict__ out)
{
    __shared__ float cs[4][32 * 33];

    const int bid = blockIdx.x;
    const int nt = bid & 3, mt = bid >> 2;
    const int tid = threadIdx.x, w = tid >> 6, lane = tid & 63;
    const int l31 = lane & 31, hh = lane >> 5;
    const int t = w >> 1, kh = w & 1;
    const int m0 = mt * 64 + (t & 1) * 32;
    const int n0 = nt * 64 + (t >> 1) * 32;

    const u16* ar = Abf + (size_t)(m0 + l31) * 256 + kh*128 + 4*hh;
    const u16* br = WT + (size_t)(1024 + n0 + l31) * 256 + kh*128 + 4*hh;

    f16v acc;
#pragma unroll
    for (int r = 0; r < 16; ++r) acc[r] = 0.f;

#pragma unroll
    for (int ks = 0; ks < 8; ++ks) {
        s4v aa = *(const s4v*)(ar + ks*16);
        s4v ab = *(const s4v*)(ar + ks*16 + 8);
        s4v ba = *(const s4v*)(br + ks*16);
        s4v bb = *(const s4v*)(br + ks*16 + 8);
        acc = MFMA(aa, ba, acc);
        acc = MFMA(ab, bb, acc);
    }

    if (kh == 0) {
#pragma unroll
        for (int r = 0; r < 16; ++r) {
            const int il = (r & 3) + 8*(r >> 2) + 4*hh;
            cs[t][il*33 + l31] = acc[r];
        }
    }
    __syncthreads();
    if (kh == 1) {
        const float bv = bout[n0 + l31];
#pragma unroll
        for (int r = 0; r < 16; ++r) {
            const int il = (r & 3) + 8*(r >> 2) + 4*hh;
            const int m = m0 + il;
            out[(size_t)m * 256 + n0 + l31] = acc[r] + cs[t][il*33 + l31] + bv;
        }
    }
}

// ---------------------------------------------------------------------------
extern "C" void kernel_launch(void* const* d_in, const int* in_sizes, int n_in,
                              void* d_out, int out_size, void* d_ws, size_t ws_size,
                              hipStream_t stream) {
    const float* x    = (const float*)d_in[0];
    const float* Wq   = (const float*)d_in[1];
    const float* Wkv  = (const float*)d_in[2];
    const float* Wout = (const float*)d_in[3];
    const float* bout = (const float*)d_in[4];
    const float* Wg   = (const float*)d_in[5];
    const float* bg   = (const float*)d_in[6];
    const float* lq1  = (const float*)d_in[7];
    const float* lk1  = (const float*)d_in[8];
    const float* lq2  = (const float*)d_in[9];
    const float* lk2  = (const float*)d_in[10];
    const float* lng  = (const float*)d_in[11];
    const float* lnb  = (const float*)d_in[12];

    // ws: WT[1280*256] | xbf | Qb | Kb | Vb (u16) | Gb (f32) | Abf (u16)
    u16*   WT  = (u16*)d_ws;
    u16*   xbf = WT + 327680;
    u16*   Qb  = xbf + 1048576;
    u16*   Kb  = Qb + 1048576;
    u16*   Vb  = Kb + 1048576;
    float* Gb  = (float*)(Vb + 1048576);
    u16*   Abf = (u16*)(Gb + 1048576);

    hipLaunchKernelGGL(prep_kernel, dim3(144), dim3(256), 0, stream,
                       Wq, Wkv, Wg, Wout, x, WT, xbf);
    hipLaunchKernelGGL(proj_kernel, dim3(512), dim3(256), 0, stream,
                       xbf, WT, bg, Qb, Kb, Vb, Gb);
    hipLaunchKernelGGL(attn_kernel, dim3(512), dim3(256), 0, stream,
                       Qb, Kb, Vb, Gb, lq1, lk1, lq2, lk2, lng, lnb, Abf);
    hipLaunchKernelGGL(out_kernel, dim3(256), dim3(512), 0, stream,
                       Abf, WT, bout, (float*)d_out);
}

// Round 14
// 158.457 us; speedup vs baseline: 1.1093x; 1.1093x over previous
//
#include <hip/hip_runtime.h>
#include <hip/hip_bf16.h>

#define LAMBDA_INIT_F 0.35550906759096927f
#define ONE_MINUS_LI  0.64449093240903073f
#define QSCALE 0.36067376022224085f   // 0.25 * log2(e): exp(s) == exp2(s_scaled)

typedef unsigned short u16;
typedef unsigned int   u32;
typedef short s4v  __attribute__((ext_vector_type(4)));
typedef float f16v __attribute__((ext_vector_type(16)));

__device__ __forceinline__ u16 f2bf(float f) {
    __hip_bfloat16 h = __float2bfloat16(f);
    return *reinterpret_cast<u16*>(&h);
}
__device__ __forceinline__ u32 pk2bf(float lo, float hi) {
    return (u32)f2bf(lo) | ((u32)f2bf(hi) << 16);
}
union U2S { u32 u[2]; s4v s; };
__device__ __forceinline__ s4v mks4(u32 a, u32 b) { U2S x; x.u[0]=a; x.u[1]=b; return x.s; }

// raw v_exp_f32 (1 inst) — libm exp2f is ~8 inst without -ffast-math
__device__ __forceinline__ float fexp2(float x) {
#if __has_builtin(__builtin_amdgcn_exp2f)
    return __builtin_amdgcn_exp2f(x);
#else
    float r; asm volatile("v_exp_f32 %0, %1\n\ts_nop 1" : "=v"(r) : "v"(x)); return r;
#endif
}

#define MFMA(a,b,c) __builtin_amdgcn_mfma_f32_32x32x8bf16_1k((a),(b),(c),0,0,0)

// ---------------------------------------------------------------------------
// Kernel 0: prep. Blocks 0..79: transpose f32 weights -> bf16 WT[1280][256]
// (16 WT-rows per block). Blocks 80..143: x (f32) -> xbf (bf16), 64 rows each.
// ---------------------------------------------------------------------------
__global__ __launch_bounds__(256) void prep_kernel(
    const float* __restrict__ Wq, const float* __restrict__ Wkv,
    const float* __restrict__ Wg, const float* __restrict__ Wout,
    const float* __restrict__ x,
    u16* __restrict__ WT, u16* __restrict__ xbf)
{
    const int bid = blockIdx.x;
    const int tid = threadIdx.x;

    if (bid >= 80) {               // x convert: rows (bid-80)*64 .. +63
        const int r0 = (bid - 80) * 64;
        const float2* src = (const float2*)(x + (size_t)r0 * 256);
        u32* dst = (u32*)(xbf + (size_t)r0 * 256);
        for (int idx = tid; idx < 64 * 128; idx += 256) {
            float2 v = src[idx];
            dst[idx] = pk2bf(v.x, v.y);
        }
        return;
    }

    __shared__ u16 tile[16 * 258];
    const int n0g = bid * 16;      // WT row base (0..1279)
    const float* src; int cols; int ncol0;
    if      (n0g < 256)  { src = Wq;   cols = 256; ncol0 = n0g; }
    else if (n0g < 768)  { src = Wkv;  cols = 512; ncol0 = n0g - 256; }
    else if (n0g < 1024) { src = Wg;   cols = 256; ncol0 = n0g - 768; }
    else                 { src = Wout; cols = 256; ncol0 = n0g - 1024; }

    const float* srow = src + (size_t)tid * cols + ncol0;
#pragma unroll
    for (int j = 0; j < 8; ++j) {
        const float2 v = *(const float2*)(srow + 2*j);
        tile[(2*j + 0) * 258 + tid] = f2bf(v.x);
        tile[(2*j + 1) * 258 + tid] = f2bf(v.y);
    }
    __syncthreads();

    const u32* t32 = (const u32*)tile;           // row stride 129 u32
    const int nn = tid >> 4, part = tid & 15;
    u32* dst = (u32*)WT + (size_t)(n0g + nn) * 128 + part * 8;
    const u32* s2 = t32 + nn * 129 + part * 8;
#pragma unroll
    for (int j = 0; j < 8; ++j) dst[j] = s2[j];
}

// ---------------------------------------------------------------------------
// Kernel 1: MFMA projections. C[4096,1024] = xbf @ [Wq|Wk|Wv|Wg], epilogue
// scatters to Qb (bf16, pre-scaled QSCALE), Kb, Vb (bf16), Gb (f32 sigmoid).
// Grid 512 = 32 mt x 16 nt; 4 waves, wave w = rows mt*128+w*32, 2 n-subtiles.
// ---------------------------------------------------------------------------
__global__ __launch_bounds__(256) void proj_kernel(
    const u16* __restrict__ x, const u16* __restrict__ WT,
    const float* __restrict__ bg,
    u16* __restrict__ Qb, u16* __restrict__ Kb,
    u16* __restrict__ Vb, float* __restrict__ Gb)
{
    const int bid = blockIdx.x;
    const int nt = bid & 15, mt = bid >> 4;
    const int tid = threadIdx.x, w = tid >> 6, lane = tid & 63;
    const int l31 = lane & 31, hh = lane >> 5;
    const int m0 = mt * 128 + w * 32;
    const int n0 = nt * 64;

    const u16* xr  = x  + (size_t)(m0 + l31) * 256 + 4*hh;
    const u16* br0 = WT + (size_t)(n0 + l31) * 256 + 4*hh;
    const u16* br1 = WT + (size_t)(n0 + 32 + l31) * 256 + 4*hh;

    f16v a0, a1;
#pragma unroll
    for (int r = 0; r < 16; ++r) { a0[r] = 0.f; a1[r] = 0.f; }

#pragma unroll
    for (int ks = 0; ks < 16; ++ks) {
        s4v xa  = *(const s4v*)(xr  + ks*16);
        s4v xb  = *(const s4v*)(xr  + ks*16 + 8);
        s4v w0a = *(const s4v*)(br0 + ks*16);
        s4v w0b = *(const s4v*)(br0 + ks*16 + 8);
        s4v w1a = *(const s4v*)(br1 + ks*16);
        s4v w1b = *(const s4v*)(br1 + ks*16 + 8);
        a0 = MFMA(xa, w0a, a0); a0 = MFMA(xb, w0b, a0);
        a1 = MFMA(xa, w1a, a1); a1 = MFMA(xb, w1b, a1);
    }

    const int cat = nt >> 2;    // 0=Q 1=K 2=V 3=G
#pragma unroll
    for (int ns = 0; ns < 2; ++ns) {
        const f16v& acc = ns ? a1 : a0;
        const int n = nt * 64 + ns * 32 + l31;
#pragma unroll
        for (int r = 0; r < 16; ++r) {
            const int il = (r & 3) + 8*(r >> 2) + 4*hh;
            const int R = m0 + il;
            const int b = R >> 11, i = R & 2047;
            const float v = acc[r];
            if (cat == 0) {
                const int h = n >> 4, d = n & 15;
                Qb[((size_t)(b*16 + h) * 2048 + i) * 16 + d] = f2bf(v * QSCALE);
            } else if (cat == 1) {
                const int nk = n - 256, h = nk >> 4, d = nk & 15;
                Kb[((size_t)(b*16 + h) * 2048 + i) * 16 + d] = f2bf(v);
            } else if (cat == 2) {
                const int nv = n - 512, hv = nv >> 5, d2 = nv & 31;
                Vb[((size_t)(b*8 + hv) * 2048 + i) * 32 + d2] = f2bf(v);
            } else {
                const int gcol = n - 768;
                const float t = v + bg[gcol];
                Gb[(size_t)R * 256 + gcol] = 1.0f / (1.0f + __expf(-t));
            }
        }
    }
}

// ---------------------------------------------------------------------------
// Kernel 2: MFMA flash differential attention + LN + gate -> bf16 A.
// Grid 1024 = (b, ho, 32-q-rows), 512 threads = 8 waves = (jq = w>>1, s = w&1):
// subhead s, j-quarter jq (16 chunks of 32 keys). Per round the block stages
// 4 chunk-slots (slot q staged by wave-pair q = threads q*128..q*128+127);
// each slot: K(s=0) 32x18 + K(s=1) 32x18 + V^T 32x34 u16 = 1120 u32.
// 2 buffers x 4480 u32 = 35.8 KB -> 4 blocks/CU x 8 waves = 32 waves/CU.
// S^T = MFMA(A=K, B=Q); P = exp2 (raw v_exp_f32) truncation-packed (v_perm)
// into the PV A-operand. 8-way cross-wave combine + diff + LN + gate via LDS.
// ---------------------------------------------------------------------------
__global__ __launch_bounds__(512, 8) void attn_kernel(
    const u16* __restrict__ Q, const u16* __restrict__ K,
    const u16* __restrict__ V, const float* __restrict__ G,
    const float* __restrict__ lq1, const float* __restrict__ lk1,
    const float* __restrict__ lq2, const float* __restrict__ lk2,
    const float* __restrict__ gamma, const float* __restrict__ beta,
    u16* __restrict__ A)
{
    // staging: 2 buf x 4 slots x 1120 u32 = 8960 u32 = 35.8 KB
    // combine (reuse): 8 x (32x33 f32) O + 8x32 f32 l = 8704 f32
    __shared__ float smemf[8960];
    u16* st  = (u16*)smemf;
    u32* stu = (u32*)smemf;

    const int bid = blockIdx.x;
    const int itile = bid & 63;
    const int combo = bid >> 6;
    const int ho = combo & 7, b = combo >> 3;
    const int i0 = itile * 32;

    const int tid = threadIdx.x, w = tid >> 6, lane = tid & 63;
    const int l31 = lane & 31, hh = lane >> 5;
    const int s = w & 1, jq = w >> 1;

    const u16* Vg = V + (size_t)(b*8 + ho) * 2048 * 32;
    const u16* Qg = Q + ((size_t)(b*16 + 2*ho + s) * 2048 + (i0 + l31)) * 16;
    const s4v qf0 = *(const s4v*)(Qg + 4*hh);
    const s4v qf1 = *(const s4v*)(Qg + 8 + 4*hh);

    // --- staging assignment: wave-pair qp stages slot qp ---
    const int qp = tid >> 7;              // slot 0..3 (chunks qp*16 + t)
    const int pid = tid & 127;
    // K: 2 subheads x 32 rows x 8 u32; thread -> (ksub, krow, kseg): 4 u32
    const int ksub = pid >> 6, krow = (pid >> 1) & 31, kseg = pid & 1;
    const u32* kgp = (const u32*)(K + (size_t)(b*16 + 2*ho + ksub) * 2048 * 16)
                     + (size_t)qp * 4096 + krow * 8 + kseg * 4;
    // V: 32 rows(j) x 16 u32; thread -> (vj, vseg): 4 u32 = d vseg*8..+7
    const int vj = pid >> 2, vseg = pid & 3;
    const u32* vgp = (const u32*)Vg + (size_t)qp * 8192 + vj * 16 + vseg * 4;

    // LDS offsets: slot base qp*1120 u32 / qp*2240 u16; buffer +p*4480/+p*8960
    const int kw_off = qp*1120 + ksub*288 + krow*9 + kseg*4;   // u32 write
    const int vw_u16 = qp*2240 + 1152 + vj;                    // u16 write, +d*34
    const int vd0 = vseg * 8;
    const int kr_off = jq*1120 + s*288 + l31*9 + 2*hh;         // u32 read
    const int vr_off = jq*1120 + 576 + l31*17;                 // u32 read, +4f+2hh

    f16v oacc;
#pragma unroll
    for (int r = 0; r < 16; ++r) oacc[r] = 0.f;
    float la0 = 0.f, la1 = 0.f;

    {   // prologue: stage round 0 into buffer 0
        u32 k0 = kgp[0], k1 = kgp[1], k2 = kgp[2], k3 = kgp[3];
        u32 v0 = vgp[0], v1 = vgp[1], v2 = vgp[2], v3 = vgp[3];
        u32* kd = stu + kw_off;
        kd[0]=k0; kd[1]=k1; kd[2]=k2; kd[3]=k3;
        u16* vd = st + vw_u16;
        vd[(vd0+0)*34] = (u16)(v0 & 0xffff); vd[(vd0+1)*34] = (u16)(v0 >> 16);
        vd[(vd0+2)*34] = (u16)(v1 & 0xffff); vd[(vd0+3)*34] = (u16)(v1 >> 16);
        vd[(vd0+4)*34] = (u16)(v2 & 0xffff); vd[(vd0+5)*34] = (u16)(v2 >> 16);
        vd[(vd0+6)*34] = (u16)(v3 & 0xffff); vd[(vd0+7)*34] = (u16)(v3 >> 16);
    }

    for (int t = 0; t < 16; ++t) {
        __syncthreads();
        const int p = t & 1, pn = 1 - p;
        const int tt = (t + 1) & 15;          // branchless wrap

        const u32* kp = kgp + (size_t)tt * 256;
        u32 nk0=kp[0], nk1=kp[1], nk2=kp[2], nk3=kp[3];
        const u32* vp = vgp + (size_t)tt * 512;
        u32 nv0=vp[0], nv1=vp[1], nv2=vp[2], nv3=vp[3];

        const u32* kb2 = stu + p*4480 + kr_off;
        const u32* vb2 = stu + p*4480 + vr_off;

        f16v sc;
#pragma unroll
        for (int r = 0; r < 16; ++r) sc[r] = 0.f;
        {
            s4v kf0 = mks4(kb2[0], kb2[1]);
            sc = MFMA(kf0, qf0, sc);
            s4v kf1 = mks4(kb2[4], kb2[5]);
            sc = MFMA(kf1, qf1, sc);
        }
        float pv[16];
#pragma unroll
        for (int r = 0; r < 16; ++r) pv[r] = fexp2(sc[r]);
        la0 += pv[0];  la0 += pv[1];  la0 += pv[2];  la0 += pv[3];
        la1 += pv[4];  la1 += pv[5];  la1 += pv[6];  la1 += pv[7];
        la0 += pv[8];  la0 += pv[9];  la0 += pv[10]; la0 += pv[11];
        la1 += pv[12]; la1 += pv[13]; la1 += pv[14]; la1 += pv[15];
#pragma unroll
        for (int f = 0; f < 4; ++f) {
            u32 plo = __builtin_amdgcn_perm(__float_as_uint(pv[4*f+1]),
                                            __float_as_uint(pv[4*f+0]), 0x07060302);
            u32 phi = __builtin_amdgcn_perm(__float_as_uint(pv[4*f+3]),
                                            __float_as_uint(pv[4*f+2]), 0x07060302);
            s4v pf = mks4(plo, phi);
            s4v vf = mks4(vb2[4*f + 2*hh], vb2[4*f + 2*hh + 1]);
            oacc = MFMA(pf, vf, oacc);
        }

        {   // stage round tt into buffer pn
            u32* kd = stu + pn*4480 + kw_off;
            kd[0]=nk0; kd[1]=nk1; kd[2]=nk2; kd[3]=nk3;
            u16* vd = st + pn*8960 + vw_u16;
            vd[(vd0+0)*34] = (u16)(nv0 & 0xffff); vd[(vd0+1)*34] = (u16)(nv0 >> 16);
            vd[(vd0+2)*34] = (u16)(nv1 & 0xffff); vd[(vd0+3)*34] = (u16)(nv1 >> 16);
            vd[(vd0+4)*34] = (u16)(nv2 & 0xffff); vd[(vd0+5)*34] = (u16)(nv2 >> 16);
            vd[(vd0+6)*34] = (u16)(nv3 & 0xffff); vd[(vd0+7)*34] = (u16)(nv3 >> 16);
        }
    }
    const float lacc = la0 + la1;

    __syncthreads();                  // staging dead; reuse LDS for combine
    float ltot = lacc + __shfl_xor(lacc, 32);
    float* ob = smemf + w * 1056;
#pragma unroll
    for (int r = 0; r < 16; ++r) {
        const int il = (r & 3) + 8*(r >> 2) + 4*hh;   // local query row
        ob[il*33 + l31] = oacc[r];                    // col = d = l31
    }
    if (lane < 32) smemf[8448 + w*32 + l31] = ltot;
    __syncthreads();

    if (tid < 32) {
        const int ii = tid;
        float l1 = 0.f, l2 = 0.f;
#pragma unroll
        for (int q = 0; q < 4; ++q) {
            l1 += smemf[8448 + (2*q + 0)*32 + ii];
            l2 += smemf[8448 + (2*q + 1)*32 + ii];
        }

        float sA = 0.f, sB = 0.f;
#pragma unroll
        for (int d = 0; d < 16; ++d) {
            sA += lq1[d] * lk1[d];
            sB += lq2[d] * lk2[d];
        }
        const float lam = __expf(sA) - __expf(sB) + LAMBDA_INIT_F;
        const float c1 = 1.f / l1, c2 = lam / l2;

        float od[32], mu = 0.f;
#pragma unroll
        for (int d = 0; d < 32; ++d) {
            float o1 = 0.f, o2 = 0.f;
#pragma unroll
            for (int q = 0; q < 4; ++q) {
                o1 += smemf[(2*q + 0)*1056 + ii*33 + d];
                o2 += smemf[(2*q + 1)*1056 + ii*33 + d];
            }
            od[d] = o1 * c1 - o2 * c2;
            mu += od[d];
        }
        mu *= (1.f / 32.f);
        float var = 0.f;
#pragma unroll
        for (int d = 0; d < 32; ++d) { const float t2 = od[d] - mu; var += t2 * t2; }
        var *= (1.f / 32.f);
        const float rs = rsqrtf(var + 1e-5f);

        const int R = b*2048 + i0 + ii;
        const float* Gr = G + (size_t)R * 256 + ho*32;
        u16* Ar = A + (size_t)R * 256 + ho*32;
#pragma unroll
        for (int d = 0; d < 32; ++d) {
            const float val = (od[d] - mu)*rs*gamma[d] + beta[d];
            Ar[d] = f2bf(val * ONE_MINUS_LI * Gr[d]);
        }
    }
}

// ---------------------------------------------------------------------------
// Kernel 3: out = A(bf16) @ Wout + bout -> f32. Grid 256, 512 threads:
// 8 waves = 4 (32x32) tiles x 2 K-halves; LDS combine of the K-split.
// ---------------------------------------------------------------------------
__global__ __launch_bounds__(512) void out_kernel(
    const u16* __restrict__ Abf, const u16* __restrict__ WT,
    const float* __restrict__ bout, float* __restrict__ out)
{
    __shared__ float cs[4][32 * 33];

    const int bid = blockIdx.x;
    const int nt = bid & 3, mt = bid >> 2;
    const int tid = threadIdx.x, w = tid >> 6, lane = tid & 63;
    const int l31 = lane & 31, hh = lane >> 5;
    const int t = w >> 1, kh = w & 1;
    const int m0 = mt * 64 + (t & 1) * 32;
    const int n0 = nt * 64 + (t >> 1) * 32;

    const u16* ar = Abf + (size_t)(m0 + l31) * 256 + kh*128 + 4*hh;
    const u16* br = WT + (size_t)(1024 + n0 + l31) * 256 + kh*128 + 4*hh;

    f16v acc;
#pragma unroll
    for (int r = 0; r < 16; ++r) acc[r] = 0.f;

#pragma unroll
    for (int ks = 0; ks < 8; ++ks) {
        s4v aa = *(const s4v*)(ar + ks*16);
        s4v ab = *(const s4v*)(ar + ks*16 + 8);
        s4v ba = *(const s4v*)(br + ks*16);
        s4v bb = *(const s4v*)(br + ks*16 + 8);
        acc = MFMA(aa, ba, acc);
        acc = MFMA(ab, bb, acc);
    }

    if (kh == 0) {
#pragma unroll
        for (int r = 0; r < 16; ++r) {
            const int il = (r & 3) + 8*(r >> 2) + 4*hh;
            cs[t][il*33 + l31] = acc[r];
        }
    }
    __syncthreads();
    if (kh == 1) {
        const float bv = bout[n0 + l31];
#pragma unroll
        for (int r = 0; r < 16; ++r) {
            const int il = (r & 3) + 8*(r >> 2) + 4*hh;
            const int m = m0 + il;
            out[(size_t)m * 256 + n0 + l31] = acc[r] + cs[t][il*33 + l31] + bv;
        }
    }
}

// ---------------------------------------------------------------------------
extern "C" void kernel_launch(void* const* d_in, const int* in_sizes, int n_in,
                              void* d_out, int out_size, void* d_ws, size_t ws_size,
                              hipStream_t stream) {
    const float* x    = (const float*)d_in[0];
    const float* Wq   = (const float*)d_in[1];
    const float* Wkv  = (const float*)d_in[2];
    const float* Wout = (const float*)d_in[3];
    const float* bout = (const float*)d_in[4];
    const float* Wg   = (const float*)d_in[5];
    const float* bg   = (const float*)d_in[6];
    const float* lq1  = (const float*)d_in[7];
    const float* lk1  = (const float*)d_in[8];
    const float* lq2  = (const float*)d_in[9];
    const float* lk2  = (const float*)d_in[10];
    const float* lng  = (const float*)d_in[11];
    const float* lnb  = (const float*)d_in[12];

    // ws: WT[1280*256] | xbf | Qb | Kb | Vb (u16) | Gb (f32) | Abf (u16)
    u16*   WT  = (u16*)d_ws;
    u16*   xbf = WT + 327680;
    u16*   Qb  = xbf + 1048576;
    u16*   Kb  = Qb + 1048576;
    u16*   Vb  = Kb + 1048576;
    float* Gb  = (float*)(Vb + 1048576);
    u16*   Abf = (u16*)(Gb + 1048576);

    hipLaunchKernelGGL(prep_kernel, dim3(144), dim3(256), 0, stream,
                       Wq, Wkv, Wg, Wout, x, WT, xbf);
    hipLaunchKernelGGL(proj_kernel, dim3(512), dim3(256), 0, stream,
                       xbf, WT, bg, Qb, Kb, Vb, Gb);
    hipLaunchKernelGGL(attn_kernel, dim3(1024), dim3(512), 0, stream,
                       Qb, Kb, Vb, Gb, lq1, lk1, lq2, lk2, lng, lnb, Abf);
    hipLaunchKernelGGL(out_kernel, dim3(256), dim3(512), 0, stream,
                       Abf, WT, bout, (float*)d_out);
}